// Round 5
// baseline (300.602 us; speedup 1.0000x reference)
//
#include <hip/hip_runtime.h>
#include <math.h>

#define NDET 512
#define NCLS 81
#define MM   784      // 28*28
#define PROBS_ELEMS (2 * NDET * MM)   // 802816
#define NMS_TH 0.5
#define EPS_D  1e-4
#define SDD 114       // LDS row stride in DOUBLES: even (16B-aligned double2
                      // rows); row-to-row = 228 banks = 4 (mod 32), so the
                      // 8-distinct-row/col read patterns below are conflict-free

// ---------------- ws layout (bytes) ----------------
// 0      : double u[2][512]            (8192)
// 8192   : int order[512]              (2048)
// 16384  : u32 bits32[2][512][16]      (65536)   == u64 bits[2][512][8]
// total  : 81920 bytes

// K12: blocks 0..255 -> gather+sigmoid, one WAVE per (side,detection) mask
//      (4 masks/block, shfl reduction, no barriers).
//      block 256 -> single-block bitonic sort of scores (runs concurrently).
__global__ __launch_bounds__(256) void k12_fused(
    const float* __restrict__ left, const float* __restrict__ right,
    const float* __restrict__ scores, const int* __restrict__ labels,
    float* __restrict__ out, double* __restrict__ u, int* __restrict__ order) {
  if (blockIdx.x == 256) {
    // ---- bitonic sort of 512 (score desc, idx asc), 256 threads ----
    __shared__ float sk[NDET];
    __shared__ int   si[NDET];
    int t = threadIdx.x;
    for (int e = t; e < NDET; e += 256) { sk[e] = scores[e]; si[e] = e; }
    __syncthreads();
    for (int k = 2; k <= NDET; k <<= 1) {
      for (int j = k >> 1; j > 0; j >>= 1) {
        for (int e = t; e < NDET; e += 256) {
          int p = e ^ j;
          if (p > e) {
            bool dir = ((e & k) == 0);   // descending block
            float sa = sk[e], sb = sk[p];
            int ia = si[e], ib = si[p];
            bool aBeforeB = (sa > sb) || (sa == sb && ia < ib);
            bool doSwap = dir ? (!aBeforeB) : aBeforeB;
            if (doSwap) { sk[e] = sb; si[e] = ib; sk[p] = sa; si[p] = ia; }
          }
        }
        __syncthreads();
      }
    }
    for (int e = t; e < NDET; e += 256) order[e] = si[e];
    return;
  }

  // ---- gather + sigmoid + fp64 row-sum, one wave per mask ----
  int wv = threadIdx.x >> 6;
  int lane = threadIdx.x & 63;
  int m = (blockIdx.x << 2) | wv;     // 0..1023
  int s = m >> 9;                     // side
  int n = m & 511;                    // detection
  const float* src = (s == 0) ? left : right;
  int lab = labels[n];
  const float4* in4 = (const float4*)(src + ((size_t)n * NCLS + lab) * MM);
  float4* out4 = (float4*)(out + ((size_t)s * NDET + n) * MM);
  double local = 0.0;
  for (int i = lane; i < MM / 4; i += 64) {   // 196 float4
    float4 v = in4[i];
    float4 r;
    r.x = 1.0f / (1.0f + expf(-v.x));
    r.y = 1.0f / (1.0f + expf(-v.y));
    r.z = 1.0f / (1.0f + expf(-v.z));
    r.w = 1.0f / (1.0f + expf(-v.w));
    out4[i] = r;
    local += (double)r.x + (double)r.y + (double)r.z + (double)r.w;
  }
#pragma unroll
  for (int off = 32; off > 0; off >>= 1)
    local += __shfl_down(local, off, 64);
  if (lane == 0) u[s * NDET + n] = local;
}

// K3: upper-triangular 32x32 tiles of the sorted iou comparison matrix.
// fp64 VALU. 512 threads = 8 waves, K SPLIT 8-WAYS (each wave: full 32x32
// tile over 98 k-values, 4x4 per-thread register tile). Wave-partial buffer
// Cp OVERLAYS the dead Asd/Bsd arena after the main loop -> LDS ~60.7 KB,
// __launch_bounds__(512,4) caps VGPR at 128 -> 2 blocks/CU: 2 waves/SIMD
// hide LDS latency and all 272 blocks are co-resident (no straggler round).
// Double-typed LDS staging (cvt once), global->reg prefetch of next chunk.
__global__ __launch_bounds__(512, 4) void k3_iou(
    const float* __restrict__ P,        // d_out probs base (2*512*784 f32)
    const double* __restrict__ u,
    const int* __restrict__ order,
    unsigned int* __restrict__ bits32) {
  int bi = blockIdx.x;                  // 0..271
  int s = bi / 136;
  int tri = bi % 136;
  int ti = 0, rem = tri;
  while (rem >= 16 - ti) { rem -= 16 - ti; ti++; }
  int tj = ti + rem;                    // tj >= ti

  // arena: [Asd 32*114 | Bsd 32*114] during main loop (58368 B),
  //        [Cp 7*32*33]              after it        (59136 B).
  __shared__ __align__(16) double arena[7 * 32 * 33];
  double (*Asd)[SDD] = (double (*)[SDD])arena;
  double (*Bsd)[SDD] = (double (*)[SDD])(arena + 32 * SDD);
  double (*Cp)[33]   = (double (*)[33])arena;     // overlays, used post-loop
  __shared__ int oi[32], oj[32];
  __shared__ double den05[32];          // NMS_TH * (u + EPS)  (exact: *0.5)
  __shared__ unsigned char pred[32][32];

  int t = threadIdx.x;
  if (t < 32) {
    int r = order[ti * 32 + t];
    oi[t] = r;
    den05[t] = 0.5 * (u[s * NDET + r] + EPS_D);
    oj[t] = order[tj * 32 + t];
  }
  __syncthreads();

  const float* Pside = P + (size_t)s * NDET * MM;

  // staging slots: chunk = 32 rows x 112 floats (28 float4/row) for A and B.
  // 1792 float4 total / 512 threads = 3.5 -> 4 slots, slot 3 only for t<256.
  const float4* gsrc[4];
  double* ldst[4];
  int nslot = (t < 256) ? 4 : 3;
#pragma unroll
  for (int i = 0; i < 4; i++) {
    int idx = t + 512 * i;              // 0..2047, valid < 1792
    if (idx < 1792) {
      int ab = (idx >= 896);
      int idc = ab ? (idx - 896) : idx;
      int r = idc / 28;
      int c4 = idc - r * 28;
      int o = ab ? oj[r] : oi[r];
      gsrc[i] = (const float4*)(Pside + (size_t)o * MM) + c4;
      ldst[i] = ab ? &Bsd[r][4 * c4] : &Asd[r][4 * c4];
    } else {
      gsrc[i] = (const float4*)(Pside);   // unused
      ldst[i] = &Asd[0][0];
    }
  }

  float4 pf[4];
  for (int i = 0; i < nslot; i++) pf[i] = gsrc[i][0];   // chunk 0

  int wv = t >> 6;                      // k-eighth 0..7
  int lane = t & 63;
  int tx = lane & 7;                    // col group: cols {tx+8j}
  int ty = lane >> 3;                   // row group: rows {ty+8i}
  int kb = 14 * wv;                     // this wave's k-slice within a chunk

  double acc[4][4];
#pragma unroll
  for (int i = 0; i < 4; i++)
#pragma unroll
    for (int j = 0; j < 4; j++) acc[i][j] = 0.0;

  for (int kc = 0; kc < 7; kc++) {      // 7 * 112 = 784
    // commit prefetched chunk to LDS (f32 -> f64 once here)
    for (int i = 0; i < nslot; i++) {
      float4 v = pf[i];
      double2 d0; d0.x = (double)v.x; d0.y = (double)v.y;
      double2 d1; d1.x = (double)v.z; d1.y = (double)v.w;
      *(double2*)(ldst[i])     = d0;
      *(double2*)(ldst[i] + 2) = d1;
    }
    __syncthreads();
    if (kc < 6) {
      for (int i = 0; i < nslot; i++) pf[i] = gsrc[i][(kc + 1) * 28];
    }
    // this wave's 14 k-values of the chunk, 2 at a time
#pragma unroll
    for (int kp = 0; kp < 7; kp++) {
      double2 av[4], bv[4];
#pragma unroll
      for (int i = 0; i < 4; i++)
        av[i] = *(const double2*)&Asd[ty + 8 * i][kb + 2 * kp];
#pragma unroll
      for (int j = 0; j < 4; j++)
        bv[j] = *(const double2*)&Bsd[tx + 8 * j][kb + 2 * kp];
#pragma unroll
      for (int i = 0; i < 4; i++)
#pragma unroll
        for (int j = 0; j < 4; j++) {
          acc[i][j] = fma(av[i].x, bv[j].x, acc[i][j]);
          acc[i][j] = fma(av[i].y, bv[j].y, acc[i][j]);
        }
    }
    __syncthreads();
  }

  // ---- combine wave k-partials (fp64) via overlay, threshold, pack ----
  if (wv > 0) {
#pragma unroll
    for (int i = 0; i < 4; i++)
#pragma unroll
      for (int j = 0; j < 4; j++)
        Cp[(wv - 1) * 32 + ty + 8 * i][tx + 8 * j] = acc[i][j];
  }
  __syncthreads();
  if (wv == 0) {
#pragma unroll
    for (int i = 0; i < 4; i++) {
      int r = ty + 8 * i;
#pragma unroll
      for (int j = 0; j < 4; j++) {
        int c = tx + 8 * j;
        double v = acc[i][j];
#pragma unroll
        for (int p = 0; p < 7; p++) v += Cp[p * 32 + r][c];
        pred[r][c] = (v >= den05[r]) ? 1 : 0;
      }
    }
  }
  __syncthreads();
  if (t < 32) {
    unsigned m = 0;
#pragma unroll
    for (int c = 0; c < 32; c++) m |= ((unsigned)pred[t][c]) << c;
    bits32[((size_t)s * NDET + ti * 32 + t) * 16 + tj] = m;
  }
}

// K4: greedy suppression (both sides) + combine. One block, 512 threads.
// Every lane of wave 0/1 holds the FULL 512-bit suppression mask in 8 u64
// registers (redundantly identical across lanes) -> active check is a
// register bit-test + scalar branch; suppressed rows cost ~8 instructions.
__global__ __launch_bounds__(512) void k4_greedy(
    const unsigned long long* __restrict__ bits,  // [2][512][8]
    const int* __restrict__ order,
    const double* __restrict__ u,
    float* __restrict__ outKeep) {
  __shared__ unsigned long long B[2 * NDET * 8];   // 64 KiB
  __shared__ unsigned char keepO[2 * NDET];        // by original index
  int t = threadIdx.x;

  // stage + mask j<=i (also kills garbage from never-written lower tiles)
  for (int e = t; e < 2 * NDET * 8; e += 512) {
    unsigned long long w = bits[e];
    int g = e & 7;
    int i = (e >> 3) & 511;
    int gi = i >> 6;
    if (g < gi) {
      w = 0ull;
    } else if (g == gi) {
      int li = i & 63;
      w = (li == 63) ? 0ull : (w & (~0ull << (li + 1)));
    }
    B[e] = w;
  }
  __syncthreads();

  int wv = t >> 6;
  int lane = t & 63;
  if (wv < 2) {
    int s = wv;
    const unsigned long long* Bside = B + (size_t)s * NDET * 8;
    unsigned long long S0 = 0, S1 = 0, S2 = 0, S3 = 0,
                       S4 = 0, S5 = 0, S6 = 0, S7 = 0;

#define GROUP(G, SG, ORS)                                              \
    for (int li = 0; li < 64; li++) {                                  \
      unsigned act = (unsigned)((SG >> li) & 1ull);                    \
      if (__builtin_amdgcn_readfirstlane(act) == 0) {                  \
        const unsigned long long* row = Bside + ((((G) << 6) | li) << 3); \
        ORS                                                            \
      }                                                                \
    }
    GROUP(0, S0, { S0 |= row[0]; S1 |= row[1]; S2 |= row[2]; S3 |= row[3];
                   S4 |= row[4]; S5 |= row[5]; S6 |= row[6]; S7 |= row[7]; })
    GROUP(1, S1, { S1 |= row[1]; S2 |= row[2]; S3 |= row[3];
                   S4 |= row[4]; S5 |= row[5]; S6 |= row[6]; S7 |= row[7]; })
    GROUP(2, S2, { S2 |= row[2]; S3 |= row[3];
                   S4 |= row[4]; S5 |= row[5]; S6 |= row[6]; S7 |= row[7]; })
    GROUP(3, S3, { S3 |= row[3];
                   S4 |= row[4]; S5 |= row[5]; S6 |= row[6]; S7 |= row[7]; })
    GROUP(4, S4, { S4 |= row[4]; S5 |= row[5]; S6 |= row[6]; S7 |= row[7]; })
    GROUP(5, S5, { S5 |= row[5]; S6 |= row[6]; S7 |= row[7]; })
    GROUP(6, S6, { S6 |= row[6]; S7 |= row[7]; })
    GROUP(7, S7, { S7 |= row[7]; })
#undef GROUP

    unsigned long long Sarr[8] = {S0, S1, S2, S3, S4, S5, S6, S7};
#pragma unroll
    for (int g = 0; g < 8; g++) {
      int c = (g << 6) | lane;                    // sorted position
      keepO[s * NDET + order[c]] =
          (unsigned char)(((Sarr[g] >> lane) & 1ull) ^ 1ull);
    }
  }
  __syncthreads();

  if (t < NDET) {
    bool valid = (u[t] > 0.0) && (u[NDET + t] > 0.0);
    outKeep[t] = (valid && keepO[t] && keepO[NDET + t]) ? 1.0f : 0.0f;
  }
}

extern "C" void kernel_launch(void* const* d_in, const int* in_sizes, int n_in,
                              void* d_out, int out_size, void* d_ws, size_t ws_size,
                              hipStream_t stream) {
  const float* left   = (const float*)d_in[0];
  const float* right  = (const float*)d_in[1];
  const float* scores = (const float*)d_in[2];
  const int*   labels = (const int*)d_in[3];
  float* out = (float*)d_out;

  char* ws = (char*)d_ws;
  double* u                = (double*)(ws + 0);
  int* order               = (int*)(ws + 8192);
  unsigned int* bits32     = (unsigned int*)(ws + 16384);
  unsigned long long* bits = (unsigned long long*)(ws + 16384);

  k12_fused<<<257, 256, 0, stream>>>(left, right, scores, labels, out, u, order);
  k3_iou<<<272, 512, 0, stream>>>(out, u, order, bits32);
  k4_greedy<<<1, 512, 0, stream>>>(bits, order, u, out + PROBS_ELEMS);
}

// Round 6
// 280.854 us; speedup vs baseline: 1.0703x; 1.0703x over previous
//
#include <hip/hip_runtime.h>
#include <math.h>

#define NDET 512
#define NCLS 81
#define MM   784      // 28*28
#define PROBS_ELEMS (2 * NDET * MM)   // 802816
#define NMS_TH 0.5
#define EPS_D  1e-4
#define SDD 114       // LDS row stride in DOUBLES: even (16B-aligned double2
                      // rows); row-to-row = 228 banks = 4 (mod 32), so the
                      // 8-distinct-row/col read patterns below are conflict-free

// ---------------- ws layout (bytes) ----------------
// 0      : double u[2][512]            (8192)
// 8192   : int order[512]              (2048)
// 16384  : u32 bits32[2][512][16]      (65536)   == u64 bits[2][512][8]
// total  : 81920 bytes

// K12: blocks 0..255 -> gather+sigmoid, one WAVE per (side,detection) mask
//      (4 masks/block, shfl reduction, no barriers).
//      block 256 -> single-block bitonic sort of scores (runs concurrently).
__global__ __launch_bounds__(256) void k12_fused(
    const float* __restrict__ left, const float* __restrict__ right,
    const float* __restrict__ scores, const int* __restrict__ labels,
    float* __restrict__ out, double* __restrict__ u, int* __restrict__ order) {
  if (blockIdx.x == 256) {
    // ---- bitonic sort of 512 (score desc, idx asc), 256 threads ----
    __shared__ float sk[NDET];
    __shared__ int   si[NDET];
    int t = threadIdx.x;
    for (int e = t; e < NDET; e += 256) { sk[e] = scores[e]; si[e] = e; }
    __syncthreads();
    for (int k = 2; k <= NDET; k <<= 1) {
      for (int j = k >> 1; j > 0; j >>= 1) {
        for (int e = t; e < NDET; e += 256) {
          int p = e ^ j;
          if (p > e) {
            bool dir = ((e & k) == 0);   // descending block
            float sa = sk[e], sb = sk[p];
            int ia = si[e], ib = si[p];
            bool aBeforeB = (sa > sb) || (sa == sb && ia < ib);
            bool doSwap = dir ? (!aBeforeB) : aBeforeB;
            if (doSwap) { sk[e] = sb; si[e] = ib; sk[p] = sa; si[p] = ia; }
          }
        }
        __syncthreads();
      }
    }
    for (int e = t; e < NDET; e += 256) order[e] = si[e];
    return;
  }

  // ---- gather + sigmoid + fp64 row-sum, one wave per mask ----
  int wv = threadIdx.x >> 6;
  int lane = threadIdx.x & 63;
  int m = (blockIdx.x << 2) | wv;     // 0..1023
  int s = m >> 9;                     // side
  int n = m & 511;                    // detection
  const float* src = (s == 0) ? left : right;
  int lab = labels[n];
  const float4* in4 = (const float4*)(src + ((size_t)n * NCLS + lab) * MM);
  float4* out4 = (float4*)(out + ((size_t)s * NDET + n) * MM);
  double local = 0.0;
  for (int i = lane; i < MM / 4; i += 64) {   // 196 float4
    float4 v = in4[i];
    float4 r;
    r.x = 1.0f / (1.0f + expf(-v.x));
    r.y = 1.0f / (1.0f + expf(-v.y));
    r.z = 1.0f / (1.0f + expf(-v.z));
    r.w = 1.0f / (1.0f + expf(-v.w));
    out4[i] = r;
    local += (double)r.x + (double)r.y + (double)r.z + (double)r.w;
  }
#pragma unroll
  for (int off = 32; off > 0; off >>= 1)
    local += __shfl_down(local, off, 64);
  if (lane == 0) u[s * NDET + n] = local;
}

// K3: upper-triangular 32x32 tiles of the sorted iou comparison matrix.
// fp64 VALU, R4-verified compute structure: 256 threads = 4 waves, K split
// 4-ways, 4x4 per-thread register tile, 14-kp inner loop. The wave-partial
// buffer Cp OVERLAYS the dead Asd/Bsd arena (disjoint in time: Cp is first
// written after the final main-loop barrier) -> LDS ~60 KB ->
// __launch_bounds__(256,2) gives 2 blocks/CU: 2 waves/SIMD hide ds_read
// latency AND all 272 blocks are co-resident (no 16-CU straggler round).
// FMA order bit-identical to the passing R4 kernel.
__global__ __launch_bounds__(256, 2) void k3_iou(
    const float* __restrict__ P,        // d_out probs base (2*512*784 f32)
    const double* __restrict__ u,
    const int* __restrict__ order,
    unsigned int* __restrict__ bits32) {
  int bi = blockIdx.x;                  // 0..271
  int s = bi / 136;
  int tri = bi % 136;
  int ti = 0, rem = tri;
  while (rem >= 16 - ti) { rem -= 16 - ti; ti++; }
  int tj = ti + rem;                    // tj >= ti

  // arena: [Asd 32*114 | Bsd 32*114] during main loop (58368 B);
  //        [Cp 3*32*33 = 3168 dbl]   overlays the front after it.
  __shared__ __align__(16) double arena[2 * 32 * SDD];
  double (*Asd)[SDD] = (double (*)[SDD])arena;
  double (*Bsd)[SDD] = (double (*)[SDD])(arena + 32 * SDD);
  double (*Cp)[33]   = (double (*)[33])arena;     // used post-loop only
  __shared__ int oi[32], oj[32];
  __shared__ double den05[32];          // NMS_TH * (u + EPS)  (exact: *0.5)
  __shared__ unsigned char pred[32][32];

  int t = threadIdx.x;
  if (t < 32) {
    int r = order[ti * 32 + t];
    oi[t] = r;
    den05[t] = 0.5 * (u[s * NDET + r] + EPS_D);
    oj[t] = order[tj * 32 + t];
  }
  __syncthreads();

  const float* Pside = P + (size_t)s * NDET * MM;

  // staging slots: chunk = 32 rows x 112 floats (28 float4/row) for A and B.
  // 1792 float4 total / 256 threads = 7 slots each. Whole mask row (784 f32)
  // is contiguous in global, so chunk kc of a row = base + kc*112 floats.
  const float4* gsrc[7];
  double* ldst[7];
#pragma unroll
  for (int i = 0; i < 7; i++) {
    int idx = t + 256 * i;              // 0..1791
    int ab = (idx >= 896);
    int idc = ab ? (idx - 896) : idx;
    int r = idc / 28;
    int c4 = idc - r * 28;
    int o = ab ? oj[r] : oi[r];
    gsrc[i] = (const float4*)(Pside + (size_t)o * MM) + c4;
    ldst[i] = ab ? &Bsd[r][4 * c4] : &Asd[r][4 * c4];
  }

  float4 pf[7];
#pragma unroll
  for (int i = 0; i < 7; i++) pf[i] = gsrc[i][0];   // chunk 0

  int wv = t >> 6;                      // k-quarter 0..3
  int lane = t & 63;
  int tx = lane & 7;                    // col group: cols {tx+8j}
  int ty = (lane >> 3) & 7;             // row group: rows {ty+8i}
  int kb = 28 * wv;                     // this wave's k-slice within a chunk

  double acc[4][4];
#pragma unroll
  for (int i = 0; i < 4; i++)
#pragma unroll
    for (int j = 0; j < 4; j++) acc[i][j] = 0.0;

  for (int kc = 0; kc < 7; kc++) {      // 7 * 112 = 784
    // commit prefetched chunk to LDS (f32 -> f64 once here)
#pragma unroll
    for (int i = 0; i < 7; i++) {
      float4 v = pf[i];
      double2 d0; d0.x = (double)v.x; d0.y = (double)v.y;
      double2 d1; d1.x = (double)v.z; d1.y = (double)v.w;
      *(double2*)(ldst[i])     = d0;
      *(double2*)(ldst[i] + 2) = d1;
    }
    __syncthreads();
    if (kc < 6) {
#pragma unroll
      for (int i = 0; i < 7; i++) pf[i] = gsrc[i][(kc + 1) * 28];
    }
    // this wave's 28 k-values of the chunk, 2 at a time
#pragma unroll
    for (int kp = 0; kp < 14; kp++) {
      double2 av[4], bv[4];
#pragma unroll
      for (int i = 0; i < 4; i++)
        av[i] = *(const double2*)&Asd[ty + 8 * i][kb + 2 * kp];
#pragma unroll
      for (int j = 0; j < 4; j++)
        bv[j] = *(const double2*)&Bsd[tx + 8 * j][kb + 2 * kp];
#pragma unroll
      for (int i = 0; i < 4; i++)
#pragma unroll
        for (int j = 0; j < 4; j++) {
          acc[i][j] = fma(av[i].x, bv[j].x, acc[i][j]);
          acc[i][j] = fma(av[i].y, bv[j].y, acc[i][j]);
        }
    }
    __syncthreads();
  }

  // ---- combine wave k-partials (fp64) via overlay, threshold, pack ----
  if (wv > 0) {
#pragma unroll
    for (int i = 0; i < 4; i++)
#pragma unroll
      for (int j = 0; j < 4; j++)
        Cp[(wv - 1) * 32 + ty + 8 * i][tx + 8 * j] = acc[i][j];
  }
  __syncthreads();
  if (wv == 0) {
#pragma unroll
    for (int i = 0; i < 4; i++) {
      int r = ty + 8 * i;
#pragma unroll
      for (int j = 0; j < 4; j++) {
        int c = tx + 8 * j;
        double v = acc[i][j] + Cp[0 * 32 + r][c] + Cp[1 * 32 + r][c] +
                   Cp[2 * 32 + r][c];
        pred[r][c] = (v >= den05[r]) ? 1 : 0;
      }
    }
  }
  __syncthreads();
  if (t < 32) {
    unsigned m = 0;
#pragma unroll
    for (int c = 0; c < 32; c++) m |= ((unsigned)pred[t][c]) << c;
    bits32[((size_t)s * NDET + ti * 32 + t) * 16 + tj] = m;
  }
}

// K4: greedy suppression (both sides) + combine. One block, 512 threads.
// Every lane of wave 0/1 holds the FULL 512-bit suppression mask in 8 u64
// registers (redundantly identical across lanes) -> active check is a
// register bit-test + scalar branch; suppressed rows cost ~8 instructions.
__global__ __launch_bounds__(512) void k4_greedy(
    const unsigned long long* __restrict__ bits,  // [2][512][8]
    const int* __restrict__ order,
    const double* __restrict__ u,
    float* __restrict__ outKeep) {
  __shared__ unsigned long long B[2 * NDET * 8];   // 64 KiB
  __shared__ unsigned char keepO[2 * NDET];        // by original index
  int t = threadIdx.x;

  // stage + mask j<=i (also kills garbage from never-written lower tiles)
  for (int e = t; e < 2 * NDET * 8; e += 512) {
    unsigned long long w = bits[e];
    int g = e & 7;
    int i = (e >> 3) & 511;
    int gi = i >> 6;
    if (g < gi) {
      w = 0ull;
    } else if (g == gi) {
      int li = i & 63;
      w = (li == 63) ? 0ull : (w & (~0ull << (li + 1)));
    }
    B[e] = w;
  }
  __syncthreads();

  int wv = t >> 6;
  int lane = t & 63;
  if (wv < 2) {
    int s = wv;
    const unsigned long long* Bside = B + (size_t)s * NDET * 8;
    unsigned long long S0 = 0, S1 = 0, S2 = 0, S3 = 0,
                       S4 = 0, S5 = 0, S6 = 0, S7 = 0;

#define GROUP(G, SG, ORS)                                              \
    for (int li = 0; li < 64; li++) {                                  \
      unsigned act = (unsigned)((SG >> li) & 1ull);                    \
      if (__builtin_amdgcn_readfirstlane(act) == 0) {                  \
        const unsigned long long* row = Bside + ((((G) << 6) | li) << 3); \
        ORS                                                            \
      }                                                                \
    }
    GROUP(0, S0, { S0 |= row[0]; S1 |= row[1]; S2 |= row[2]; S3 |= row[3];
                   S4 |= row[4]; S5 |= row[5]; S6 |= row[6]; S7 |= row[7]; })
    GROUP(1, S1, { S1 |= row[1]; S2 |= row[2]; S3 |= row[3];
                   S4 |= row[4]; S5 |= row[5]; S6 |= row[6]; S7 |= row[7]; })
    GROUP(2, S2, { S2 |= row[2]; S3 |= row[3];
                   S4 |= row[4]; S5 |= row[5]; S6 |= row[6]; S7 |= row[7]; })
    GROUP(3, S3, { S3 |= row[3];
                   S4 |= row[4]; S5 |= row[5]; S6 |= row[6]; S7 |= row[7]; })
    GROUP(4, S4, { S4 |= row[4]; S5 |= row[5]; S6 |= row[6]; S7 |= row[7]; })
    GROUP(5, S5, { S5 |= row[5]; S6 |= row[6]; S7 |= row[7]; })
    GROUP(6, S6, { S6 |= row[6]; S7 |= row[7]; })
    GROUP(7, S7, { S7 |= row[7]; })
#undef GROUP

    unsigned long long Sarr[8] = {S0, S1, S2, S3, S4, S5, S6, S7};
#pragma unroll
    for (int g = 0; g < 8; g++) {
      int c = (g << 6) | lane;                    // sorted position
      keepO[s * NDET + order[c]] =
          (unsigned char)(((Sarr[g] >> lane) & 1ull) ^ 1ull);
    }
  }
  __syncthreads();

  if (t < NDET) {
    bool valid = (u[t] > 0.0) && (u[NDET + t] > 0.0);
    outKeep[t] = (valid && keepO[t] && keepO[NDET + t]) ? 1.0f : 0.0f;
  }
}

extern "C" void kernel_launch(void* const* d_in, const int* in_sizes, int n_in,
                              void* d_out, int out_size, void* d_ws, size_t ws_size,
                              hipStream_t stream) {
  const float* left   = (const float*)d_in[0];
  const float* right  = (const float*)d_in[1];
  const float* scores = (const float*)d_in[2];
  const int*   labels = (const int*)d_in[3];
  float* out = (float*)d_out;

  char* ws = (char*)d_ws;
  double* u                = (double*)(ws + 0);
  int* order               = (int*)(ws + 8192);
  unsigned int* bits32     = (unsigned int*)(ws + 16384);
  unsigned long long* bits = (unsigned long long*)(ws + 16384);

  k12_fused<<<257, 256, 0, stream>>>(left, right, scores, labels, out, u, order);
  k3_iou<<<272, 256, 0, stream>>>(out, u, order, bits32);
  k4_greedy<<<1, 512, 0, stream>>>(bits, order, u, out + PROBS_ELEMS);
}